// Round 1
// baseline (307.577 us; speedup 1.0000x reference)
//
#include <hip/hip_runtime.h>

// SimpleDIN fused kernel — fp32 baseline, one block per batch element.
//
// Key algebraic simplification: feats = [beh, tgt, beh*tgt, beh-tgt] (K=256)
//   feats @ W1 == beh @ W_eff + bias_eff   (K=64)
//   W_eff[d,j]   = W1[d,j] + tgt[d]*W1[128+d,j] + W1[192+d,j]
//   bias_eff[j]  = b1[j] + sum_d tgt[d]*(W1[64+d,j] - W1[192+d,j])
// att_b2 cancels in softmax -> dropped.

#define B_SZ   4096
#define S_SZ   200
#define D_SZ   64
#define H_SZ   80     // attention hidden
#define STRIDE 68     // LDS row stride (floats): 68*4=272 bytes, 16B aligned

struct LdsLayout {
    float beh[S_SZ][STRIDE];     // 54400 B  behavior embeddings
    float wefft[H_SZ][STRIDE];   // 21760 B  W_eff transposed [j][d]
    float tgt[D_SZ];             // target item embedding
    float w2l[H_SZ];             // att_w2
    float bias_eff[H_SZ];
    float scores[S_SZ];          // logits -> exp values
    float x[2 * D_SZ];           // [user_emb | pooled]
    float h1[64];
    float h2[32];
    float pooled_part[4][D_SZ];
    float red[8];                // cross-wave reduce scratch
};                               // total = 79808 B -> 2 blocks/CU

extern "C" __global__ __launch_bounds__(256, 2)
void din_fused(const int* __restrict__ user_ids,
               const int* __restrict__ item_ids,
               const int* __restrict__ seq,
               const float* __restrict__ user_table,
               const float* __restrict__ item_table,
               const float* __restrict__ att_w1,
               const float* __restrict__ att_b1,
               const float* __restrict__ att_w2,
               const float* __restrict__ pred_w1,
               const float* __restrict__ pred_b1,
               const float* __restrict__ pred_w2,
               const float* __restrict__ pred_b2,
               const float* __restrict__ pred_w3,
               const float* __restrict__ pred_b3,
               float* __restrict__ out)
{
    __shared__ LdsLayout L;
    const int b = blockIdx.x;
    const int t = threadIdx.x;

    // ---- phase 0: small per-block loads ----
    const int uid = user_ids[b];
    const int iid = item_ids[b];
    if (t < D_SZ) {
        L.tgt[t] = item_table[(size_t)iid * D_SZ + t];
    } else if (t < 2 * D_SZ) {
        L.x[t - D_SZ] = user_table[(size_t)uid * D_SZ + (t - D_SZ)];
    } else if (t < 2 * D_SZ + H_SZ) {
        L.w2l[t - 2 * D_SZ] = att_w2[t - 2 * D_SZ];
    }

    // ---- phase 1: gather behavior embeddings (200 rows x 64 f32) ----
    // 16 float4 per row; consecutive lanes cover one row -> 256B coalesced
    for (int slot = t; slot < S_SZ * 16; slot += 256) {
        const int s = slot >> 4;
        const int q = slot & 15;
        const int row = seq[b * S_SZ + s];
        const float4 v = *reinterpret_cast<const float4*>(
            item_table + (size_t)row * D_SZ + q * 4);
        *reinterpret_cast<float4*>(&L.beh[s][q * 4]) = v;
    }
    __syncthreads();

    // ---- phase 2: W_eff (transposed) + bias_eff ----
    for (int i = t; i < D_SZ * H_SZ; i += 256) {
        const int d = i / H_SZ;
        const int j = i - d * H_SZ;      // consecutive lanes -> coalesced W1 reads
        const float w = att_w1[d * H_SZ + j]
                      + L.tgt[d] * att_w1[(128 + d) * H_SZ + j]
                      + att_w1[(192 + d) * H_SZ + j];
        L.wefft[j][d] = w;
    }
    if (t < H_SZ) {
        float acc = att_b1[t];
        for (int d = 0; d < D_SZ; ++d)
            acc += L.tgt[d] * (att_w1[(64 + d) * H_SZ + t]
                             - att_w1[(192 + d) * H_SZ + t]);
        L.bias_eff[t] = acc;
    }
    __syncthreads();

    // ---- phase 3: h = relu(beh @ W_eff + bias_eff); logits = h @ w2 ----
    // 8x5 register tiles; 16 j-groups of 5 -> deterministic shfl tree reduce
    {
        const int sl = t >> 4;   // 0..15 : s-group slot
        const int jg = t & 15;   // 0..15 : j-group
        const int j0 = jg * 5;
        for (int it = 0; it < 2; ++it) {
            const int sg = it * 16 + sl;       // 0..31, active when sg<25
            if (sg * 8 < S_SZ) {
                const int s0 = sg * 8;
                float acc[8][5];
                #pragma unroll
                for (int si = 0; si < 8; ++si)
                    #pragma unroll
                    for (int ji = 0; ji < 5; ++ji) acc[si][ji] = 0.f;

                for (int dq = 0; dq < D_SZ; dq += 4) {
                    float4 a[8], w[5];
                    #pragma unroll
                    for (int si = 0; si < 8; ++si)
                        a[si] = *reinterpret_cast<const float4*>(&L.beh[s0 + si][dq]);
                    #pragma unroll
                    for (int ji = 0; ji < 5; ++ji)
                        w[ji] = *reinterpret_cast<const float4*>(&L.wefft[j0 + ji][dq]);
                    #pragma unroll
                    for (int si = 0; si < 8; ++si) {
                        #pragma unroll
                        for (int ji = 0; ji < 5; ++ji) {
                            acc[si][ji] = fmaf(a[si].x, w[ji].x, acc[si][ji]);
                            acc[si][ji] = fmaf(a[si].y, w[ji].y, acc[si][ji]);
                            acc[si][ji] = fmaf(a[si].z, w[ji].z, acc[si][ji]);
                            acc[si][ji] = fmaf(a[si].w, w[ji].w, acc[si][ji]);
                        }
                    }
                }
                #pragma unroll
                for (int si = 0; si < 8; ++si) {
                    float p = 0.f;
                    #pragma unroll
                    for (int ji = 0; ji < 5; ++ji) {
                        const float h = acc[si][ji] + L.bias_eff[j0 + ji];
                        p += fmaxf(h, 0.f) * L.w2l[j0 + ji];
                    }
                    #pragma unroll
                    for (int off = 1; off < 16; off <<= 1)
                        p += __shfl_xor(p, off);
                    if (jg == 0) L.scores[s0 + si] = p;
                }
            }
        }
    }
    __syncthreads();

    // ---- phase 4: softmax over 200 logits ----
    const float raw = (t < S_SZ) ? L.scores[t] : -1e30f;
    float m = raw;
    #pragma unroll
    for (int off = 32; off; off >>= 1) m = fmaxf(m, __shfl_xor(m, off));
    if ((t & 63) == 0) L.red[t >> 6] = m;
    __syncthreads();
    m = fmaxf(fmaxf(L.red[0], L.red[1]), fmaxf(L.red[2], L.red[3]));
    const float e = (t < S_SZ) ? __expf(raw - m) : 0.f;
    if (t < S_SZ) L.scores[t] = e;
    float ssum = e;
    #pragma unroll
    for (int off = 32; off; off >>= 1) ssum += __shfl_xor(ssum, off);
    if ((t & 63) == 0) L.red[4 + (t >> 6)] = ssum;
    __syncthreads();
    const float inv = 1.f / (L.red[4] + L.red[5] + L.red[6] + L.red[7]);

    // ---- phase 5: pooled = (sum_s e_s * beh[s,:]) * inv ----
    {
        const int g = t >> 6;      // wave id: s-range [50g, 50g+50)
        const int d = t & 63;
        float part = 0.f;
        for (int s = 50 * g; s < 50 * (g + 1); ++s)
            part += L.scores[s] * L.beh[s][d];
        L.pooled_part[g][d] = part;
    }
    __syncthreads();
    if (t < D_SZ) {
        L.x[D_SZ + t] = (L.pooled_part[0][t] + L.pooled_part[1][t]
                       + L.pooled_part[2][t] + L.pooled_part[3][t]) * inv;
    }
    __syncthreads();

    // ---- phase 6: prediction MLP 128 -> 64 -> 32 -> 1 ----
    if (t < 64) {
        float acc = pred_b1[t];
        for (int k = 0; k < 128; ++k)
            acc = fmaf(L.x[k], pred_w1[k * 64 + t], acc);
        L.h1[t] = fmaxf(acc, 0.f);
    }
    __syncthreads();
    if (t < 32) {
        float acc = pred_b2[t];
        for (int k = 0; k < 64; ++k)
            acc = fmaf(L.h1[k], pred_w2[k * 32 + t], acc);
        L.h2[t] = fmaxf(acc, 0.f);
    }
    __syncthreads();
    if (t == 0) {
        float acc = pred_b3[0];
        for (int k = 0; k < 32; ++k)
            acc = fmaf(L.h2[k], pred_w3[k], acc);
        out[b] = 1.f / (1.f + __expf(-acc));
    }
}

extern "C" void kernel_launch(void* const* d_in, const int* in_sizes, int n_in,
                              void* d_out, int out_size, void* d_ws, size_t ws_size,
                              hipStream_t stream)
{
    const int*   user_ids   = (const int*)  d_in[0];
    const int*   item_ids   = (const int*)  d_in[1];
    const int*   seq        = (const int*)  d_in[2];
    const float* user_table = (const float*)d_in[3];
    const float* item_table = (const float*)d_in[4];
    const float* att_w1     = (const float*)d_in[5];
    const float* att_b1     = (const float*)d_in[6];
    const float* att_w2     = (const float*)d_in[7];
    // d_in[8] = att_b2: cancels in softmax, unused
    const float* pred_w1    = (const float*)d_in[9];
    const float* pred_b1    = (const float*)d_in[10];
    const float* pred_w2    = (const float*)d_in[11];
    const float* pred_b2    = (const float*)d_in[12];
    const float* pred_w3    = (const float*)d_in[13];
    const float* pred_b3    = (const float*)d_in[14];
    float* out = (float*)d_out;

    din_fused<<<B_SZ, 256, 0, stream>>>(user_ids, item_ids, seq,
                                        user_table, item_table,
                                        att_w1, att_b1, att_w2,
                                        pred_w1, pred_b1, pred_w2, pred_b2,
                                        pred_w3, pred_b3, out);
}

// Round 2
// 89.275 us; speedup vs baseline: 3.4453x; 3.4453x over previous
//
#include <hip/hip_runtime.h>

// SimpleDIN fused kernel v2 — bf16 MFMA attention GEMM, bf16 LDS tiles.
//
// Algebra: feats=[beh,tgt,beh*tgt,beh-tgt] (K=256) collapses:
//   feats @ W1 == beh @ W_eff + bias_eff   (K=64)
//   W_eff[d,j]  = W1[d,j] + tgt[d]*W1[128+d,j] + W1[192+d,j]
//   bias_eff[j] = b1[j] + sum_d tgt[d]*(W1[64+d,j] - W1[192+d,j])
// att_b2 cancels in softmax.
//
// Phase 3 uses v_mfma_f32_16x16x32_bf16: M=208(13 tiles) N=80(5) K=64(2).
// beh & W_eff^T live in LDS as bf16, rows of 64 bf16 (128B), XOR-swizzled
// at 16B granularity: granule' = granule ^ (row&7)  -> b128 reads/writes
// hit all 8 granule positions across lanes (bank-optimal).

#define B_SZ  4096
#define S_SZ  200
#define S_PAD 208
#define D_SZ  64
#define H_SZ  80

typedef __attribute__((ext_vector_type(8))) short    bf16x8;
typedef __attribute__((ext_vector_type(8))) unsigned short u16x8;
typedef __attribute__((ext_vector_type(4))) float    f32x4;

struct __align__(16) Lds {
    unsigned short beh[S_PAD * 64];    // 26624 B, swizzled bf16 [s][d]
    unsigned short wefft[H_SZ * 64];   // 10240 B, swizzled bf16 [j][d]
    float tgt[D_SZ];
    float w2l[H_SZ];
    float bias_eff[H_SZ];
    float scores[S_SZ];
    float x[2 * D_SZ];
    float h1[64];
    float h2[32];
    float pooled_part[4][D_SZ];
    float red[8];
};                                      // ~40.5 KB -> 4 blocks/CU

__device__ __forceinline__ int swz_gran(int row, int g) {
    // index (in u16 units) of 16B granule g of row, swizzled
    return row * 64 + ((g ^ (row & 7)) << 3);
}
__device__ __forceinline__ int swz_elem(int row, int col) {
    return row * 64 + (((col >> 3) ^ (row & 7)) << 3) + (col & 7);
}
__device__ __forceinline__ unsigned short f2bf(float f) {
    union { float f; unsigned int u; } v; v.f = f;
    unsigned int u = v.u;
    u += 0x7fffu + ((u >> 16) & 1u);          // round-to-nearest-even
    return (unsigned short)(u >> 16);
}
__device__ __forceinline__ float bf2f(unsigned short h) {
    union { unsigned int u; float f; } v; v.u = ((unsigned int)h) << 16;
    return v.f;
}

extern "C" __global__ __launch_bounds__(256, 4)
void din_fused(const int* __restrict__ user_ids,
               const int* __restrict__ item_ids,
               const int* __restrict__ seq,
               const float* __restrict__ user_table,
               const float* __restrict__ item_table,
               const float* __restrict__ att_w1,
               const float* __restrict__ att_b1,
               const float* __restrict__ att_w2,
               const float* __restrict__ pred_w1,
               const float* __restrict__ pred_b1,
               const float* __restrict__ pred_w2,
               const float* __restrict__ pred_b2,
               const float* __restrict__ pred_w3,
               const float* __restrict__ pred_b3,
               float* __restrict__ out)
{
    __shared__ Lds L;
    const int b = blockIdx.x;
    const int t = threadIdx.x;

    // ---- phase 0: small per-block loads ----
    const int uid = user_ids[b];
    const int iid = item_ids[b];
    if (t < D_SZ) {
        L.tgt[t] = item_table[(size_t)iid * D_SZ + t];
    } else if (t < 2 * D_SZ) {
        L.x[t - D_SZ] = user_table[(size_t)uid * D_SZ + (t - D_SZ)];
    } else if (t < 2 * D_SZ + H_SZ) {
        L.w2l[t - 2 * D_SZ] = att_w2[t - 2 * D_SZ];
    }

    // ---- phase 1: gather behavior rows -> bf16 LDS (swizzled) ----
    // task = (s, granule g of 8 bf16); lane reads 32B f32, writes 16B bf16
    for (int slot = t; slot < S_PAD * 8; slot += 256) {
        const int s = slot >> 3;
        const int g = slot & 7;
        u16x8 v;
        if (s < S_SZ) {
            const int row = seq[b * S_SZ + s];
            const float4* src = reinterpret_cast<const float4*>(
                item_table + (size_t)row * D_SZ + g * 8);
            const float4 p0 = src[0];
            const float4 p1 = src[1];
            v[0] = f2bf(p0.x); v[1] = f2bf(p0.y);
            v[2] = f2bf(p0.z); v[3] = f2bf(p0.w);
            v[4] = f2bf(p1.x); v[5] = f2bf(p1.y);
            v[6] = f2bf(p1.z); v[7] = f2bf(p1.w);
        } else {
            v = (u16x8)0;                       // zero pad rows 200..207
        }
        *reinterpret_cast<u16x8*>(&L.beh[swz_gran(s, g)]) = v;
    }
    __syncthreads();

    // ---- phase 2: W_eff^T (bf16, swizzled) + bias_eff ----
    for (int i = t; i < D_SZ * H_SZ; i += 256) {
        const int d = i / H_SZ;
        const int j = i - d * H_SZ;             // consecutive lanes: coalesced
        const float w = att_w1[d * H_SZ + j]
                      + L.tgt[d] * att_w1[(128 + d) * H_SZ + j]
                      + att_w1[(192 + d) * H_SZ + j];
        L.wefft[swz_elem(j, d)] = f2bf(w);
    }
    if (t < H_SZ) {
        float acc = att_b1[t];
        for (int d = 0; d < D_SZ; ++d)
            acc += L.tgt[d] * (att_w1[(64 + d) * H_SZ + t]
                             - att_w1[(192 + d) * H_SZ + t]);
        L.bias_eff[t] = acc;
    }
    __syncthreads();

    // ---- phase 3: MFMA  C[s,j] = beh @ W_eff; logits = relu(C+b)·w2 ----
    {
        const int w  = t >> 6;                  // wave 0..3
        const int l  = t & 63;
        const int lr = l & 15;                  // M-row / N-col within tile
        const int ks = l >> 4;                  // k-slot 0..3

        // B fragments (shared across all M-tiles): 5 ntiles x 2 ksteps
        bf16x8 bf[10];
        #pragma unroll
        for (int nt = 0; nt < 5; ++nt) {
            const int j = nt * 16 + lr;
            #pragma unroll
            for (int kk = 0; kk < 2; ++kk)
                bf[nt * 2 + kk] = *reinterpret_cast<const bf16x8*>(
                    &L.wefft[swz_gran(j, kk * 4 + ks)]);
        }

        for (int mt = w; mt < 13; mt += 4) {
            const int srow = mt * 16 + lr;
            const bf16x8 a0 = *reinterpret_cast<const bf16x8*>(
                &L.beh[swz_gran(srow, ks)]);
            const bf16x8 a1 = *reinterpret_cast<const bf16x8*>(
                &L.beh[swz_gran(srow, 4 + ks)]);
            f32x4 acc[5];
            #pragma unroll
            for (int nt = 0; nt < 5; ++nt)
                acc[nt] = (f32x4){0.f, 0.f, 0.f, 0.f};
            #pragma unroll
            for (int nt = 0; nt < 5; ++nt) {
                acc[nt] = __builtin_amdgcn_mfma_f32_16x16x32_bf16(
                    a0, bf[nt * 2 + 0], acc[nt], 0, 0, 0);
                acc[nt] = __builtin_amdgcn_mfma_f32_16x16x32_bf16(
                    a1, bf[nt * 2 + 1], acc[nt], 0, 0, 0);
            }
            // epilogue: relu(c+bias)*w2, sum over j (16 lanes x 5 ntiles)
            #pragma unroll
            for (int r = 0; r < 4; ++r) {
                const int s = mt * 16 + ks * 4 + r;   // D row mapping
                float p = 0.f;
                #pragma unroll
                for (int nt = 0; nt < 5; ++nt) {
                    const int j = nt * 16 + lr;       // D col mapping
                    const float h = acc[nt][r] + L.bias_eff[j];
                    p += fmaxf(h, 0.f) * L.w2l[j];
                }
                p += __shfl_xor(p, 1);
                p += __shfl_xor(p, 2);
                p += __shfl_xor(p, 4);
                p += __shfl_xor(p, 8);
                if (lr == 0 && s < S_SZ) L.scores[s] = p;
            }
        }
    }
    __syncthreads();

    // ---- phase 4: softmax over 200 logits ----
    const float raw = (t < S_SZ) ? L.scores[t] : -1e30f;
    float m = raw;
    #pragma unroll
    for (int off = 32; off; off >>= 1) m = fmaxf(m, __shfl_xor(m, off));
    if ((t & 63) == 0) L.red[t >> 6] = m;
    __syncthreads();
    m = fmaxf(fmaxf(L.red[0], L.red[1]), fmaxf(L.red[2], L.red[3]));
    const float e = (t < S_SZ) ? __expf(raw - m) : 0.f;
    if (t < S_SZ) L.scores[t] = e;
    float ssum = e;
    #pragma unroll
    for (int off = 32; off; off >>= 1) ssum += __shfl_xor(ssum, off);
    if ((t & 63) == 0) L.red[4 + (t >> 6)] = ssum;
    __syncthreads();
    const float inv = 1.f / (L.red[4] + L.red[5] + L.red[6] + L.red[7]);

    // ---- phase 5: pooled = (sum_s e_s * beh[s,:]) * inv ----
    {
        const int g = t >> 6;
        const int d = t & 63;
        float part = 0.f;
        for (int s = 50 * g; s < 50 * (g + 1); ++s)
            part += L.scores[s] * bf2f(L.beh[swz_elem(s, d)]);
        L.pooled_part[g][d] = part;
    }
    __syncthreads();
    if (t < D_SZ) {
        L.x[D_SZ + t] = (L.pooled_part[0][t] + L.pooled_part[1][t]
                       + L.pooled_part[2][t] + L.pooled_part[3][t]) * inv;
    }
    __syncthreads();

    // ---- phase 6: prediction MLP 128 -> 64 -> 32 -> 1 ----
    if (t < 64) {
        float acc = pred_b1[t];
        for (int k = 0; k < 128; ++k)
            acc = fmaf(L.x[k], pred_w1[k * 64 + t], acc);
        L.h1[t] = fmaxf(acc, 0.f);
    }
    __syncthreads();
    if (t < 32) {
        float acc = pred_b2[t];
        for (int k = 0; k < 64; ++k)
            acc = fmaf(L.h1[k], pred_w2[k * 32 + t], acc);
        L.h2[t] = fmaxf(acc, 0.f);
    }
    __syncthreads();
    if (t == 0) {
        float acc = pred_b3[0];
        for (int k = 0; k < 32; ++k)
            acc = fmaf(L.h2[k], pred_w3[k], acc);
        out[b] = 1.f / (1.f + __expf(-acc));
    }
}

extern "C" void kernel_launch(void* const* d_in, const int* in_sizes, int n_in,
                              void* d_out, int out_size, void* d_ws, size_t ws_size,
                              hipStream_t stream)
{
    const int*   user_ids   = (const int*)  d_in[0];
    const int*   item_ids   = (const int*)  d_in[1];
    const int*   seq        = (const int*)  d_in[2];
    const float* user_table = (const float*)d_in[3];
    const float* item_table = (const float*)d_in[4];
    const float* att_w1     = (const float*)d_in[5];
    const float* att_b1     = (const float*)d_in[6];
    const float* att_w2     = (const float*)d_in[7];
    // d_in[8] = att_b2: cancels in softmax, unused
    const float* pred_w1    = (const float*)d_in[9];
    const float* pred_b1    = (const float*)d_in[10];
    const float* pred_w2    = (const float*)d_in[11];
    const float* pred_b2    = (const float*)d_in[12];
    const float* pred_w3    = (const float*)d_in[13];
    const float* pred_b3    = (const float*)d_in[14];
    float* out = (float*)d_out;

    din_fused<<<B_SZ, 256, 0, stream>>>(user_ids, item_ids, seq,
                                        user_table, item_table,
                                        att_w1, att_b1, att_w2,
                                        pred_w1, pred_b1, pred_w2, pred_b2,
                                        pred_w3, pred_b3, out);
}

// Round 3
// 86.326 us; speedup vs baseline: 3.5630x; 1.0342x over previous
//
#include <hip/hip_runtime.h>
#include <hip/hip_bf16.h>

// SimpleDIN fused kernel v3 — bf16 MFMA + VALU-diet gather/pool/MLP.
//
// Algebra: feats=[beh,tgt,beh*tgt,beh-tgt] (K=256) collapses:
//   feats @ W1 == beh @ W_eff + bias_eff   (K=64)
//   W_eff[d,j]  = W1[d,j] + tgt[d]*W1[128+d,j] + W1[192+d,j]
//   bias_eff[j] = b1[j] + sum_d tgt[d]*(W1[64+d,j] - W1[192+d,j])
// att_b2 cancels in softmax.

#define B_SZ  4096
#define S_SZ  200
#define D_SZ  64
#define H_SZ  80

typedef __attribute__((ext_vector_type(8))) short          bf16x8;
typedef __attribute__((ext_vector_type(8))) unsigned short u16x8;
typedef __attribute__((ext_vector_type(4))) float          f32x4;

struct __align__(16) Lds {
    unsigned short beh[S_SZ * 64];     // 25600 B, swizzled bf16 [s][d]
    unsigned short wefft[H_SZ * 64];   // 10240 B, swizzled bf16 [j][d]
    float tgt[D_SZ];                   // 256
    float w2l[H_SZ];                   // 320
    float bias_eff[H_SZ];              // 320
    float scores[S_SZ];                // 800
    float x[2 * D_SZ];                 // 512
    float h1[64];                      // 256
    float h2[32];                      // 128
    float pp[8 * 64];                  // 2048 (pool partials / MLP partials)
    float red[8];                      // 32
};                                      // 40512 B -> 4 blocks/CU

__device__ __forceinline__ int swz_gran(int row, int g) {
    return row * 64 + ((g ^ (row & 7)) << 3);      // u16 index of 16B granule
}
__device__ __forceinline__ int swz_elem(int row, int col) {
    return row * 64 + (((col >> 3) ^ (row & 7)) << 3) + (col & 7);
}
__device__ __forceinline__ float bits2f(unsigned int u) {
    union { unsigned int u; float f; } v; v.u = u; return v.f;
}

extern "C" __global__ __launch_bounds__(256, 4)
void din_fused(const int* __restrict__ user_ids,
               const int* __restrict__ item_ids,
               const int* __restrict__ seq,
               const float* __restrict__ user_table,
               const float* __restrict__ item_table,
               const float* __restrict__ att_w1,
               const float* __restrict__ att_b1,
               const float* __restrict__ att_w2,
               const float* __restrict__ pred_w1,
               const float* __restrict__ pred_b1,
               const float* __restrict__ pred_w2,
               const float* __restrict__ pred_b2,
               const float* __restrict__ pred_w3,
               const float* __restrict__ pred_b3,
               float* __restrict__ out)
{
    __shared__ Lds L;
    const int b = blockIdx.x;
    const int t = threadIdx.x;

    // ---- phase 0: small per-block loads ----
    const int uid = user_ids[b];
    const int iid = item_ids[b];
    if (t < D_SZ) {
        L.tgt[t] = item_table[(size_t)iid * D_SZ + t];
    } else if (t < 2 * D_SZ) {
        L.x[t - D_SZ] = user_table[(size_t)uid * D_SZ + (t - D_SZ)];
    } else if (t < 2 * D_SZ + H_SZ) {
        L.w2l[t - 2 * D_SZ] = att_w2[t - 2 * D_SZ];
    }

    // ---- phase 1: gather behavior rows -> bf16 LDS (swizzled) ----
    // task = (s, 16B granule g); lane reads 32B f32, cvt_pk, writes 16B bf16
    for (int slot = t; slot < S_SZ * 8; slot += 256) {
        const int s = slot >> 3;
        const int g = slot & 7;
        const int row = seq[b * S_SZ + s];
        const float4* src = reinterpret_cast<const float4*>(
            item_table + (size_t)row * D_SZ + g * 8);
        const float4 p0 = src[0];
        const float4 p1 = src[1];
        union { u16x8 v; __hip_bfloat162 h2[4]; } cv;
        cv.h2[0] = __float22bfloat162_rn(float2{p0.x, p0.y});
        cv.h2[1] = __float22bfloat162_rn(float2{p0.z, p0.w});
        cv.h2[2] = __float22bfloat162_rn(float2{p1.x, p1.y});
        cv.h2[3] = __float22bfloat162_rn(float2{p1.z, p1.w});
        *reinterpret_cast<u16x8*>(&L.beh[swz_gran(s, g)]) = cv.v;
    }
    __syncthreads();

    // ---- phase 2: W_eff^T (bf16, swizzled) + bias_eff ----
    // d-pairs: 32 pairs x 80 j = 2560 tasks; cvt_pk u32 stores
    for (int i = t; i < 32 * H_SZ; i += 256) {
        const int dp = i / H_SZ;
        const int j  = i - dp * H_SZ;          // consecutive lanes: coalesced
        const int d  = dp * 2;
        const float w0 = att_w1[d * H_SZ + j]
                       + L.tgt[d] * att_w1[(128 + d) * H_SZ + j]
                       + att_w1[(192 + d) * H_SZ + j];
        const float w1 = att_w1[(d + 1) * H_SZ + j]
                       + L.tgt[d + 1] * att_w1[(129 + d) * H_SZ + j]
                       + att_w1[(193 + d) * H_SZ + j];
        const __hip_bfloat162 hp = __float22bfloat162_rn(float2{w0, w1});
        *reinterpret_cast<__hip_bfloat162*>(&L.wefft[swz_elem(j, d)]) = hp;
    }
    if (t < 2 * H_SZ) {                         // 2 threads per j, 32 d each
        const int j = t >> 1;
        const int h = t & 1;
        float acc = h ? 0.f : att_b1[j];
        const int d0 = h * 32;
        for (int d = d0; d < d0 + 32; ++d)
            acc += L.tgt[d] * (att_w1[(64 + d) * H_SZ + j]
                             - att_w1[(192 + d) * H_SZ + j]);
        acc += __shfl_xor(acc, 1);
        if (h == 0) L.bias_eff[j] = acc;
    }
    __syncthreads();

    // ---- phase 3: MFMA  C[s,j] = beh @ W_eff; logits = relu(C+b)·w2 ----
    {
        const int w  = t >> 6;                  // wave 0..3
        const int l  = t & 63;
        const int lr = l & 15;                  // M-row / N-col within tile
        const int ks = l >> 4;                  // k-slot 0..3

        bf16x8 bf[10];                          // B frags: 5 ntiles x 2 ksteps
        #pragma unroll
        for (int nt = 0; nt < 5; ++nt) {
            const int j = nt * 16 + lr;
            #pragma unroll
            for (int kk = 0; kk < 2; ++kk)
                bf[nt * 2 + kk] = *reinterpret_cast<const bf16x8*>(
                    &L.wefft[swz_gran(j, kk * 4 + ks)]);
        }

        for (int mt = w; mt < 13; mt += 4) {    // tile 12 reads rows 200..207:
            const int srow = mt * 16 + lr;      // garbage rows, discarded below
            const bf16x8 a0 = *reinterpret_cast<const bf16x8*>(
                &L.beh[swz_gran(srow, ks)]);
            const bf16x8 a1 = *reinterpret_cast<const bf16x8*>(
                &L.beh[swz_gran(srow, 4 + ks)]);
            f32x4 acc[5];
            #pragma unroll
            for (int nt = 0; nt < 5; ++nt)
                acc[nt] = (f32x4){0.f, 0.f, 0.f, 0.f};
            #pragma unroll
            for (int nt = 0; nt < 5; ++nt) {
                acc[nt] = __builtin_amdgcn_mfma_f32_16x16x32_bf16(
                    a0, bf[nt * 2 + 0], acc[nt], 0, 0, 0);
                acc[nt] = __builtin_amdgcn_mfma_f32_16x16x32_bf16(
                    a1, bf[nt * 2 + 1], acc[nt], 0, 0, 0);
            }
            #pragma unroll
            for (int r = 0; r < 4; ++r) {
                const int s = mt * 16 + ks * 4 + r;
                float p = 0.f;
                #pragma unroll
                for (int nt = 0; nt < 5; ++nt) {
                    const int j = nt * 16 + lr;
                    const float h = acc[nt][r] + L.bias_eff[j];
                    p += fmaxf(h, 0.f) * L.w2l[j];
                }
                p += __shfl_xor(p, 1);
                p += __shfl_xor(p, 2);
                p += __shfl_xor(p, 4);
                p += __shfl_xor(p, 8);
                if (lr == 0 && s < S_SZ) L.scores[s] = p;
            }
        }
    }
    __syncthreads();

    // ---- phase 4: softmax over 200 logits ----
    const float raw = (t < S_SZ) ? L.scores[t] : -1e30f;
    float m = raw;
    #pragma unroll
    for (int off = 32; off; off >>= 1) m = fmaxf(m, __shfl_xor(m, off));
    if ((t & 63) == 0) L.red[t >> 6] = m;
    __syncthreads();
    m = fmaxf(fmaxf(L.red[0], L.red[1]), fmaxf(L.red[2], L.red[3]));
    const float e = (t < S_SZ) ? __expf(raw - m) : 0.f;
    if (t < S_SZ) L.scores[t] = e;
    float ssum = e;
    #pragma unroll
    for (int off = 32; off; off >>= 1) ssum += __shfl_xor(ssum, off);
    if ((t & 63) == 0) L.red[4 + (t >> 6)] = ssum;
    __syncthreads();
    const float inv = 1.f / (L.red[4] + L.red[5] + L.red[6] + L.red[7]);

    // ---- phase 5: pooled = (sum_s e_s * beh[s,:]) * inv ----
    // 8 s-phases x 32 d-pairs; u32 reads; XOR-period-8 addressing:
    // u16 idx of (s0+k, d-pair dp) = (base ^ (k<<3)) + k*64, k compile-time
    {
        const int sph = t >> 5;                 // 0..7
        const int dp  = t & 31;                 // d = 2dp, 2dp+1
        const int dg  = dp >> 2;                // granule
        const int dr2 = dp & 3;                 // u32 word in granule
        float plo = 0.f, phi = 0.f;
        for (int G = sph; G < 25; G += 8) {     // 25 groups of 8 s
            const int s0 = G * 8;
            const float4 sc0 = *reinterpret_cast<const float4*>(&L.scores[s0]);
            const float4 sc1 = *reinterpret_cast<const float4*>(&L.scores[s0 + 4]);
            const int base = s0 * 64 + (dg << 3) + dr2 * 2;   // u16 idx, k=0
            #pragma unroll
            for (int k = 0; k < 8; ++k) {
                const float a = (k < 4) ? ((k == 0) ? sc0.x : (k == 1) ? sc0.y
                                         : (k == 2) ? sc0.z : sc0.w)
                                        : ((k == 4) ? sc1.x : (k == 5) ? sc1.y
                                         : (k == 6) ? sc1.z : sc1.w);
                const unsigned int u = *reinterpret_cast<const unsigned int*>(
                    &L.beh[(base ^ (k << 3)) + k * 64]);
                plo = fmaf(a, bits2f(u << 16), plo);
                phi = fmaf(a, bits2f(u & 0xffff0000u), phi);
            }
        }
        *reinterpret_cast<float2*>(&L.pp[sph * 64 + dp * 2]) = float2{plo, phi};
    }
    __syncthreads();
    if (t < D_SZ) {
        float s = 0.f;
        #pragma unroll
        for (int ph = 0; ph < 8; ++ph) s += L.pp[ph * 64 + t];
        L.x[D_SZ + t] = s * inv;
    }
    __syncthreads();

    // ---- phase 6: prediction MLP 128 -> 64 -> 32 -> 1 (all threads) ----
    {   // h1 partials: j = t&63, k-quarter = t>>6 (32 k each)
        const int j  = t & 63;
        const int k0 = (t >> 6) * 32;
        float acc = 0.f;
        for (int k = k0; k < k0 + 32; ++k)
            acc = fmaf(L.x[k], pred_w1[k * 64 + j], acc);
        L.pp[(t >> 6) * 64 + j] = acc;
    }
    __syncthreads();
    if (t < 64) {
        const float a = pred_b1[t] + L.pp[t] + L.pp[64 + t]
                      + L.pp[128 + t] + L.pp[192 + t];
        L.h1[t] = fmaxf(a, 0.f);
    }
    __syncthreads();
    {   // h2 partials: j = t&31, k-eighth = t>>5 (8 k each)
        const int j  = t & 31;
        const int k0 = (t >> 5) * 8;
        float acc = 0.f;
        #pragma unroll
        for (int k = k0; k < k0 + 8; ++k)
            acc = fmaf(L.h1[k], pred_w2[k * 32 + j], acc);
        L.pp[256 + (t >> 5) * 32 + j] = acc;
    }
    __syncthreads();
    if (t < 32) {
        float a = pred_b2[t];
        #pragma unroll
        for (int q = 0; q < 8; ++q) a += L.pp[256 + q * 32 + t];
        float p = fmaxf(a, 0.f) * pred_w3[t];
        p += __shfl_xor(p, 1);
        p += __shfl_xor(p, 2);
        p += __shfl_xor(p, 4);
        p += __shfl_xor(p, 8);
        p += __shfl_xor(p, 16);
        if (t == 0) {
            const float z = p + pred_b3[0];
            out[b] = 1.f / (1.f + __expf(-z));
        }
    }
}

extern "C" void kernel_launch(void* const* d_in, const int* in_sizes, int n_in,
                              void* d_out, int out_size, void* d_ws, size_t ws_size,
                              hipStream_t stream)
{
    const int*   user_ids   = (const int*)  d_in[0];
    const int*   item_ids   = (const int*)  d_in[1];
    const int*   seq        = (const int*)  d_in[2];
    const float* user_table = (const float*)d_in[3];
    const float* item_table = (const float*)d_in[4];
    const float* att_w1     = (const float*)d_in[5];
    const float* att_b1     = (const float*)d_in[6];
    const float* att_w2     = (const float*)d_in[7];
    // d_in[8] = att_b2: cancels in softmax, unused
    const float* pred_w1    = (const float*)d_in[9];
    const float* pred_b1    = (const float*)d_in[10];
    const float* pred_w2    = (const float*)d_in[11];
    const float* pred_b2    = (const float*)d_in[12];
    const float* pred_w3    = (const float*)d_in[13];
    const float* pred_b3    = (const float*)d_in[14];
    float* out = (float*)d_out;

    din_fused<<<B_SZ, 256, 0, stream>>>(user_ids, item_ids, seq,
                                        user_table, item_table,
                                        att_w1, att_b1, att_w2,
                                        pred_w1, pred_b1, pred_w2, pred_b2,
                                        pred_w3, pred_b3, out);
}

// Round 4
// 86.221 us; speedup vs baseline: 3.5673x; 1.0012x over previous
//
#include <hip/hip_runtime.h>
#include <hip/hip_bf16.h>

// SimpleDIN fused kernel v4 — A-frags gathered straight to registers,
// gather latency overlapped with W_eff build (async-split, T14 pattern).
//
// Algebra: feats=[beh,tgt,beh*tgt,beh-tgt] (K=256) collapses:
//   feats @ W1 == beh @ W_eff + bias_eff   (K=64)
//   W_eff[d,j]  = W1[d,j] + tgt[d]*W1[128+d,j] + W1[192+d,j]
//   bias_eff[j] = b1[j] + sum_d tgt[d]*(W1[64+d,j] - W1[192+d,j])
// att_b2 cancels in softmax.

#define B_SZ  4096
#define S_SZ  200
#define D_SZ  64
#define H_SZ  80

typedef __attribute__((ext_vector_type(8))) short          bf16x8;
typedef __attribute__((ext_vector_type(8))) unsigned short u16x8;
typedef __attribute__((ext_vector_type(4))) float          f32x4;

struct __align__(16) Lds {
    unsigned short beh[S_SZ * 64];     // 25600 B, swizzled bf16 [s][d]
    unsigned short wefft[H_SZ * 64];   // 10240 B, swizzled bf16 [j][d]
    float tgt[D_SZ];
    float w2l[H_SZ];
    float bias_eff[H_SZ];
    float scores[S_SZ];
    float x[2 * D_SZ];
    float h1[64];
    float h2[32];
    float pp[8 * 64];
    float red[8];
};                                      // 40512 B -> 4 blocks/CU

__device__ __forceinline__ int swz_gran(int row, int g) {
    return row * 64 + ((g ^ (row & 7)) << 3);      // u16 index of 16B granule
}
__device__ __forceinline__ int swz_elem(int row, int col) {
    return row * 64 + (((col >> 3) ^ (row & 7)) << 3) + (col & 7);
}
__device__ __forceinline__ float bits2f(unsigned int u) {
    union { unsigned int u; float f; } v; v.u = u; return v.f;
}

extern "C" __global__ __launch_bounds__(256, 4)
void din_fused(const int* __restrict__ user_ids,
               const int* __restrict__ item_ids,
               const int* __restrict__ seq,
               const float* __restrict__ user_table,
               const float* __restrict__ item_table,
               const float* __restrict__ att_w1,
               const float* __restrict__ att_b1,
               const float* __restrict__ att_w2,
               const float* __restrict__ pred_w1,
               const float* __restrict__ pred_b1,
               const float* __restrict__ pred_w2,
               const float* __restrict__ pred_b2,
               const float* __restrict__ pred_w3,
               const float* __restrict__ pred_b3,
               float* __restrict__ out)
{
    __shared__ Lds L;
    const int b = blockIdx.x;
    const int t = threadIdx.x;

    const int wv = t >> 6;                  // wave 0..3
    const int l  = t & 63;
    const int lr = l & 15;                  // M-row / N-col within tile
    const int ks = l >> 4;                  // k-slot 0..3

    // ---- phase 0: small per-block loads ----
    const int uid = user_ids[b];
    const int iid = item_ids[b];
    if (t < D_SZ) {
        L.tgt[t] = item_table[(size_t)iid * D_SZ + t];
    } else if (t < 2 * D_SZ) {
        L.x[t - D_SZ] = user_table[(size_t)uid * D_SZ + (t - D_SZ)];
    } else if (t < 2 * D_SZ + H_SZ) {
        L.w2l[t - 2 * D_SZ] = att_w2[t - 2 * D_SZ];
    }

    // ---- phase 1a: issue A-frag gather loads (stay in f32 registers) ----
    // thread (wv,lr,ks), tile i: mt = wv+4i, row seq[mt*16+lr];
    // a0 covers d=8ks..8ks+7 (float4 idx 2ks,2ks+1), a1 covers d=32+8ks..
    float4 pa0[4], pa1[4], pq0[4], pq1[4];
    int  srow_[4];
    bool val_[4];
    #pragma unroll
    for (int i = 0; i < 4; ++i) {
        const int mt = wv + i * 4;
        const int srow = mt * 16 + lr;
        const bool v = (mt < 13) && (srow < S_SZ);
        srow_[i] = srow;
        val_[i] = v;
        if (v) {
            const int row = seq[b * S_SZ + srow];
            const float4* src = reinterpret_cast<const float4*>(
                item_table + (size_t)row * D_SZ);
            pa0[i] = src[2 * ks];
            pa1[i] = src[2 * ks + 1];
            pq0[i] = src[8 + 2 * ks];
            pq1[i] = src[8 + 2 * ks + 1];
        }
    }

    __syncthreads();    // L.tgt ready; gather loads remain in flight

    // ---- phase 2: W_eff^T (bf16, swizzled) + bias_eff (hides gather) ----
    #pragma unroll 2
    for (int i = t; i < 32 * H_SZ; i += 256) {
        const int dp = i / H_SZ;
        const int j  = i - dp * H_SZ;
        const int d  = dp * 2;
        const float w0 = att_w1[d * H_SZ + j]
                       + L.tgt[d] * att_w1[(128 + d) * H_SZ + j]
                       + att_w1[(192 + d) * H_SZ + j];
        const float w1 = att_w1[(d + 1) * H_SZ + j]
                       + L.tgt[d + 1] * att_w1[(129 + d) * H_SZ + j]
                       + att_w1[(193 + d) * H_SZ + j];
        const __hip_bfloat162 hp = __float22bfloat162_rn(float2{w0, w1});
        *reinterpret_cast<__hip_bfloat162*>(&L.wefft[swz_elem(j, d)]) = hp;
    }
    if (t < 2 * H_SZ) {                     // 2 threads per j, 32 d each
        const int j = t >> 1;
        const int h = t & 1;
        float acc = h ? 0.f : att_b1[j];
        const int d0 = h * 32;
        #pragma unroll 4
        for (int d = d0; d < d0 + 32; ++d)
            acc += L.tgt[d] * (att_w1[(64 + d) * H_SZ + j]
                             - att_w1[(192 + d) * H_SZ + j]);
        acc += __shfl_xor(acc, 1);
        if (h == 0) L.bias_eff[j] = acc;
    }

    // ---- phase 1b: convert gathered rows -> bf16; regs + LDS (pooling) ----
    bf16x8 A0[4], A1[4];
    #pragma unroll
    for (int i = 0; i < 4; ++i) {
        union { u16x8 v; bf16x8 bf; __hip_bfloat162 h2[4]; } c0, c1;
        if (val_[i]) {
            c0.h2[0] = __float22bfloat162_rn(float2{pa0[i].x, pa0[i].y});
            c0.h2[1] = __float22bfloat162_rn(float2{pa0[i].z, pa0[i].w});
            c0.h2[2] = __float22bfloat162_rn(float2{pa1[i].x, pa1[i].y});
            c0.h2[3] = __float22bfloat162_rn(float2{pa1[i].z, pa1[i].w});
            c1.h2[0] = __float22bfloat162_rn(float2{pq0[i].x, pq0[i].y});
            c1.h2[1] = __float22bfloat162_rn(float2{pq0[i].z, pq0[i].w});
            c1.h2[2] = __float22bfloat162_rn(float2{pq1[i].x, pq1[i].y});
            c1.h2[3] = __float22bfloat162_rn(float2{pq1[i].z, pq1[i].w});
            *reinterpret_cast<u16x8*>(&L.beh[swz_gran(srow_[i], ks)])     = c0.v;
            *reinterpret_cast<u16x8*>(&L.beh[swz_gran(srow_[i], 4 + ks)]) = c1.v;
        } else {
            c0.v = (u16x8)0;
            c1.v = (u16x8)0;
        }
        A0[i] = c0.bf;
        A1[i] = c1.bf;
    }
    __syncthreads();    // wefft + bias + beh all ready

    // ---- phase 3: MFMA  C[s,j] = beh @ W_eff; logits = relu(C+b)·w2 ----
    {
        bf16x8 bf[10];                      // B frags: 5 ntiles x 2 ksteps
        #pragma unroll
        for (int nt = 0; nt < 5; ++nt) {
            const int j = nt * 16 + lr;
            #pragma unroll
            for (int kk = 0; kk < 2; ++kk)
                bf[nt * 2 + kk] = *reinterpret_cast<const bf16x8*>(
                    &L.wefft[swz_gran(j, kk * 4 + ks)]);
        }

        #pragma unroll
        for (int i = 0; i < 4; ++i) {
            const int mt = wv + i * 4;
            if (mt >= 13) break;
            f32x4 acc[5];
            #pragma unroll
            for (int nt = 0; nt < 5; ++nt)
                acc[nt] = (f32x4){0.f, 0.f, 0.f, 0.f};
            #pragma unroll
            for (int nt = 0; nt < 5; ++nt) {
                acc[nt] = __builtin_amdgcn_mfma_f32_16x16x32_bf16(
                    A0[i], bf[nt * 2 + 0], acc[nt], 0, 0, 0);
                acc[nt] = __builtin_amdgcn_mfma_f32_16x16x32_bf16(
                    A1[i], bf[nt * 2 + 1], acc[nt], 0, 0, 0);
            }
            #pragma unroll
            for (int r = 0; r < 4; ++r) {
                const int s = mt * 16 + ks * 4 + r;
                float p = 0.f;
                #pragma unroll
                for (int nt = 0; nt < 5; ++nt) {
                    const int j = nt * 16 + lr;
                    const float h = acc[nt][r] + L.bias_eff[j];
                    p += fmaxf(h, 0.f) * L.w2l[j];
                }
                p += __shfl_xor(p, 1);
                p += __shfl_xor(p, 2);
                p += __shfl_xor(p, 4);
                p += __shfl_xor(p, 8);
                if (lr == 0 && s < S_SZ) L.scores[s] = p;
            }
        }
    }
    __syncthreads();

    // ---- phase 4: softmax over 200 logits ----
    const float raw = (t < S_SZ) ? L.scores[t] : -1e30f;
    float m = raw;
    #pragma unroll
    for (int off = 32; off; off >>= 1) m = fmaxf(m, __shfl_xor(m, off));
    if ((t & 63) == 0) L.red[t >> 6] = m;
    __syncthreads();
    m = fmaxf(fmaxf(L.red[0], L.red[1]), fmaxf(L.red[2], L.red[3]));
    const float e = (t < S_SZ) ? __expf(raw - m) : 0.f;
    if (t < S_SZ) L.scores[t] = e;
    float ssum = e;
    #pragma unroll
    for (int off = 32; off; off >>= 1) ssum += __shfl_xor(ssum, off);
    if ((t & 63) == 0) L.red[4 + (t >> 6)] = ssum;
    __syncthreads();
    const float inv = 1.f / (L.red[4] + L.red[5] + L.red[6] + L.red[7]);

    // ---- phase 5: pooled = (sum_s e_s * beh[s,:]) * inv ----
    {
        const int sph = t >> 5;                 // 0..7
        const int dp  = t & 31;                 // d = 2dp, 2dp+1
        const int dg  = dp >> 2;
        const int dr2 = dp & 3;
        float plo = 0.f, phi = 0.f;
        for (int G = sph; G < 25; G += 8) {
            const int s0 = G * 8;
            const float4 sc0 = *reinterpret_cast<const float4*>(&L.scores[s0]);
            const float4 sc1 = *reinterpret_cast<const float4*>(&L.scores[s0 + 4]);
            const int base = s0 * 64 + (dg << 3) + dr2 * 2;
            #pragma unroll
            for (int k = 0; k < 8; ++k) {
                const float a = (k < 4) ? ((k == 0) ? sc0.x : (k == 1) ? sc0.y
                                         : (k == 2) ? sc0.z : sc0.w)
                                        : ((k == 4) ? sc1.x : (k == 5) ? sc1.y
                                         : (k == 6) ? sc1.z : sc1.w);
                const unsigned int u = *reinterpret_cast<const unsigned int*>(
                    &L.beh[(base ^ (k << 3)) + k * 64]);
                plo = fmaf(a, bits2f(u << 16), plo);
                phi = fmaf(a, bits2f(u & 0xffff0000u), phi);
            }
        }
        *reinterpret_cast<float2*>(&L.pp[sph * 64 + dp * 2]) = float2{plo, phi};
    }
    __syncthreads();
    if (t < D_SZ) {
        float s = 0.f;
        #pragma unroll
        for (int ph = 0; ph < 8; ++ph) s += L.pp[ph * 64 + t];
        L.x[D_SZ + t] = s * inv;
    }
    __syncthreads();

    // ---- phase 6: prediction MLP 128 -> 64 -> 32 -> 1 (all threads) ----
    {
        const int j  = t & 63;
        const int k0 = (t >> 6) * 32;
        float acc = 0.f;
        for (int k = k0; k < k0 + 32; ++k)
            acc = fmaf(L.x[k], pred_w1[k * 64 + j], acc);
        L.pp[(t >> 6) * 64 + j] = acc;
    }
    __syncthreads();
    if (t < 64) {
        const float a = pred_b1[t] + L.pp[t] + L.pp[64 + t]
                      + L.pp[128 + t] + L.pp[192 + t];
        L.h1[t] = fmaxf(a, 0.f);
    }
    __syncthreads();
    {
        const int j  = t & 31;
        const int k0 = (t >> 5) * 8;
        float acc = 0.f;
        #pragma unroll
        for (int k = k0; k < k0 + 8; ++k)
            acc = fmaf(L.h1[k], pred_w2[k * 32 + j], acc);
        L.pp[256 + (t >> 5) * 32 + j] = acc;
    }
    __syncthreads();
    if (t < 32) {
        float a = pred_b2[t];
        #pragma unroll
        for (int q = 0; q < 8; ++q) a += L.pp[256 + q * 32 + t];
        float p = fmaxf(a, 0.f) * pred_w3[t];
        p += __shfl_xor(p, 1);
        p += __shfl_xor(p, 2);
        p += __shfl_xor(p, 4);
        p += __shfl_xor(p, 8);
        p += __shfl_xor(p, 16);
        if (t == 0) {
            const float z = p + pred_b3[0];
            out[b] = 1.f / (1.f + __expf(-z));
        }
    }
}

extern "C" void kernel_launch(void* const* d_in, const int* in_sizes, int n_in,
                              void* d_out, int out_size, void* d_ws, size_t ws_size,
                              hipStream_t stream)
{
    const int*   user_ids   = (const int*)  d_in[0];
    const int*   item_ids   = (const int*)  d_in[1];
    const int*   seq        = (const int*)  d_in[2];
    const float* user_table = (const float*)d_in[3];
    const float* item_table = (const float*)d_in[4];
    const float* att_w1     = (const float*)d_in[5];
    const float* att_b1     = (const float*)d_in[6];
    const float* att_w2     = (const float*)d_in[7];
    // d_in[8] = att_b2: cancels in softmax, unused
    const float* pred_w1    = (const float*)d_in[9];
    const float* pred_b1    = (const float*)d_in[10];
    const float* pred_w2    = (const float*)d_in[11];
    const float* pred_b2    = (const float*)d_in[12];
    const float* pred_w3    = (const float*)d_in[13];
    const float* pred_b3    = (const float*)d_in[14];
    float* out = (float*)d_out;

    din_fused<<<B_SZ, 256, 0, stream>>>(user_ids, item_ids, seq,
                                        user_table, item_table,
                                        att_w1, att_b1, att_w2,
                                        pred_w1, pred_b1, pred_w2, pred_b2,
                                        pred_w3, pred_b3, out);
}